// Round 11
// baseline (344.782 us; speedup 1.0000x reference)
//
#include <hip/hip_runtime.h>
#include <hip/hip_bf16.h>

#define N_NODES 20000
#define N_EDGES 320000
#define HD 512

typedef __attribute__((ext_vector_type(8))) short bf16x8;
typedef __attribute__((ext_vector_type(4))) float f32x4;

// ---------- bf16 helpers ----------
__device__ inline ushort f2bf(float f) {
    uint u = __float_as_uint(f);
    uint r = (u + 0x7fffu + ((u >> 16) & 1u)) >> 16;
    return (ushort)r;
}
__device__ inline uint pack2(float a, float b) {
    return (uint)f2bf(a) | ((uint)f2bf(b) << 16);
}
__device__ inline float bflo(uint u) { return __uint_as_float(u << 16); }
__device__ inline float bfhi(uint u) { return __uint_as_float(u & 0xffff0000u); }

__device__ __forceinline__ void async_load16(const void* g, void* l) {
    __builtin_amdgcn_global_load_lds(
        (const __attribute__((address_space(1))) uint*)g,
        (__attribute__((address_space(3))) uint*)l,
        16, 0, 0);
}

// ---------- gemm tile: 128x128, BK=32 (r9-proven; BK=64 was neutral) --------
// remap != nullptr: C-row gr stored at row remap[gr] (gemm1 sorted scatter).
__device__ __forceinline__ void gemm_tile(const ushort* __restrict__ A,
                                          const ushort* __restrict__ Bt,
                                          ushort* __restrict__ C,
                                          const int* __restrict__ remap,
                                          int tile, char* smem) {
    short* As = (short*)smem;
    short* Bs = (short*)(smem + 128 * 32 * 2);
    const int tid = threadIdx.x;
    const int lane = tid & 63;
    const int wave = tid >> 6;
    const int l15 = lane & 15;
    const int q = lane >> 4;
    const int wrow = wave >> 1, wcol = wave & 1;
    const int row0 = (tile >> 2) * 128;
    const int col0 = (tile & 3) * 128;

    const int srow = lane >> 2;
    const int kc   = (lane & 3) ^ ((lane >> 3) & 3);
    const int sl   = (l15 >> 1) & 3;

    f32x4 acc[4][4] = {};

    for (int k0 = 0; k0 < HD; k0 += 32) {
        #pragma unroll
        for (int l = 0; l < 2; ++l) {
            const int rbase = wave * 32 + l * 16;
            const ushort* ga = &A [(size_t)(row0 + rbase + srow) * HD + k0 + kc * 8];
            const ushort* gb = &Bt[(size_t)(col0 + rbase + srow) * HD + k0 + kc * 8];
            async_load16(ga, &As[rbase * 32]);
            async_load16(gb, &Bs[rbase * 32]);
        }
        __syncthreads();
        bf16x8 aF[4], bF[4];
        #pragma unroll
        for (int i = 0; i < 4; ++i)
            aF[i] = *(bf16x8*)&As[(wrow * 64 + i * 16 + l15) * 32 + (q ^ sl) * 8];
        #pragma unroll
        for (int j = 0; j < 4; ++j)
            bF[j] = *(bf16x8*)&Bs[(wcol * 64 + j * 16 + l15) * 32 + (q ^ sl) * 8];
        #pragma unroll
        for (int i = 0; i < 4; ++i)
            #pragma unroll
            for (int j = 0; j < 4; ++j)
                acc[i][j] = __builtin_amdgcn_mfma_f32_16x16x32_bf16(aF[i], bF[j], acc[i][j], 0, 0, 0);
        __syncthreads();
    }
    #pragma unroll
    for (int i = 0; i < 4; ++i) {
        #pragma unroll
        for (int r = 0; r < 4; ++r) {
            int gr = row0 + wrow * 64 + i * 16 + q * 4 + r;
            if (gr < N_NODES) {
                int orow = remap ? remap[gr] : gr;
                #pragma unroll
                for (int j = 0; j < 4; ++j) {
                    int gc = col0 + wcol * 64 + j * 16 + l15;
                    C[(size_t)orow * HD + gc] = f2bf(acc[i][j][r]);
                }
            }
        }
    }
}

// ---------- prep: cvt x | wt transpose | edge histogram -----------------
#define NB_CVT 5000
#define NB_WT  192
#define NB_HIST 1250
__global__ __launch_bounds__(256) void prep_k(const float* __restrict__ x,
                                              ushort* __restrict__ xb,
                                              const float* __restrict__ W1,
                                              const float* __restrict__ W2,
                                              const float* __restrict__ W3,
                                              ushort* __restrict__ T1,
                                              ushort* __restrict__ T2,
                                              ushort* __restrict__ T3,
                                              const int* __restrict__ rows,
                                              int* __restrict__ deg) {
    __shared__ float t[64][65];
    const int b = blockIdx.x;
    const int tid = threadIdx.x;
    if (b < NB_CVT) {
        int c = b * 256 + tid;
        const float4* p = (const float4*)x + (size_t)c * 2;
        float4 a = p[0], q = p[1];
        uint4 o;
        o.x = pack2(a.x, a.y); o.y = pack2(a.z, a.w);
        o.z = pack2(q.x, q.y); o.w = pack2(q.z, q.w);
        ((uint4*)xb)[c] = o;
    } else if (b < NB_CVT + NB_WT) {
        int idx = b - NB_CVT;
        int layer = idx >> 6, rem = idx & 63;
        const float* W = (layer == 0) ? W1 : (layer == 1) ? W2 : W3;
        ushort* T      = (layer == 0) ? T1 : (layer == 1) ? T2 : T3;
        int kb = (rem >> 3) * 64, nb = (rem & 7) * 64;
        int c = tid & 63, r4 = tid >> 6;
        #pragma unroll
        for (int l = 0; l < 16; ++l) {
            int r = l * 4 + r4;
            t[r][c] = W[(size_t)(kb + r) * HD + nb + c];
        }
        __syncthreads();
        #pragma unroll
        for (int l = 0; l < 16; ++l) {
            int r = l * 4 + r4;
            T[(size_t)(nb + r) * HD + kb + c] = f2bf(t[c][r]);
        }
    } else {
        int e = (b - NB_CVT - NB_WT) * 256 + tid;  // 1250*256 == N_EDGES
        atomicAdd(&deg[rows[e]], 1);
    }
}

// ---------- scan: degree-sort relabeling, one workgroup (proven r8) ---------
__global__ __launch_bounds__(1024) void scan_k(const int* __restrict__ deg,
                                               int* __restrict__ rowstart,
                                               int* __restrict__ cursor,
                                               int* __restrict__ inv) {
    __shared__ int hist[256];
    __shared__ int boff0[256];
    __shared__ int bcur[256];
    __shared__ int ebase[256];
    const int tid = threadIdx.x;
    if (tid < 256) hist[tid] = 0;
    __syncthreads();
    for (int base = 0; base < N_NODES; base += 1024) {   // pass 1: histogram
        int i = base + tid;
        if (i < N_NODES) {
            int d = deg[i]; if (d > 255) d = 255;
            atomicAdd(&hist[d], 1);
        }
    }
    __syncthreads();
    if (tid == 0) {
        int a = 0, e = 0;
        for (int d = 0; d < 256; ++d) {
            boff0[d] = a; bcur[d] = a; ebase[d] = e;
            a += hist[d]; e += hist[d] * d;
        }
    }
    __syncthreads();
    for (int base = 0; base < N_NODES; base += 1024) {   // pass 2: inv scatter
        int i = base + tid;
        if (i < N_NODES) {
            int d = deg[i]; if (d > 255) d = 255;
            int p = atomicAdd(&bcur[d], 1);
            inv[i] = p;
        }
    }
    __syncthreads();
    for (int base = 0; base < N_NODES; base += 1024) {   // pass 3: rowstart
        int p = base + tid;
        if (p < N_NODES) {
            int d = 0;                                    // max d: boff0[d]<=p
            #pragma unroll
            for (int step = 128; step; step >>= 1)
                if (d + step < 256 && boff0[d + step] <= p) d += step;
            int rs = ebase[d] + (p - boff0[d]) * d;
            rowstart[p] = rs;
            cursor[p]   = rs;
        }
    }
    if (tid == 0) rowstart[N_NODES] = N_EDGES;
}

// ---------- gemm1 (inv-scatter epilogue) || fill CSR (translated) -----------
__global__ __launch_bounds__(256) void gf1_k(const ushort* __restrict__ xb,
                                             const ushort* __restrict__ wt1,
                                             ushort* __restrict__ s,
                                             const int* __restrict__ rows,
                                             const int* __restrict__ cols,
                                             const float* __restrict__ vals,
                                             const int* __restrict__ inv,
                                             int* __restrict__ cursor,
                                             int2* __restrict__ csr_cv) {
    __shared__ __align__(16) char smem[16384];
    const int b = blockIdx.x;
    if (b < 628) {
        gemm_tile(xb, wt1, s, inv, b, smem);     // s lands in sorted order
    } else {
        int e = (b - 628) * 256 + threadIdx.x;   // 1250*256 == N_EDGES exactly
        int rp = inv[rows[e]];                   // sorted row id
        int cp = inv[cols[e]];                   // sorted col id (s is sorted)
        int p = atomicAdd(&cursor[rp], 1);
        csr_cv[p] = make_int2(cp, __float_as_int(vals[e]));
    }
}

// ---------- aggregate v11: 8-deep gather pipeline ---------------------------
// r10 post-mortem: agg still latency-bound (~35us vs ~10us floor, nothing
// saturated). Last depth lever: 8 metas prefetched + 8 gathers in flight per
// group per trip -> a degree-16 row completes in 2 trips instead of 4,
// halving the serial L2-round-trip chain. Sorted space keeps trip counts
// uniform across a wave, so masked-slot waste stays ~0. All static indexing
// (rule #20). Everything else (sorted space, fused pool, XCD slices, LPT)
// unchanged (proven).
__device__ inline void fma8(float* acc, uint4 v, float w) {
    acc[0] += w * bflo(v.x); acc[1] += w * bfhi(v.x);
    acc[2] += w * bflo(v.y); acc[3] += w * bfhi(v.y);
    acc[4] += w * bflo(v.z); acc[5] += w * bfhi(v.z);
    acc[6] += w * bflo(v.w); acc[7] += w * bfhi(v.w);
}

#define AGG_RPB 32
#define AGG_CHUNKS (N_NODES / AGG_RPB)           // 625 (exact)
#define AGG_BLOCKS (8 * AGG_CHUNKS)              // 5000

__global__ __launch_bounds__(256) void agg_k(const ushort* __restrict__ s,
                                             const int* __restrict__ rowstart,
                                             const int2* __restrict__ csr_cv,
                                             const float* __restrict__ bias,
                                             ushort* __restrict__ hout,
                                             float* __restrict__ pmax,
                                             float* __restrict__ psum) {
    __shared__ float red[2][4][64];              // [max|sum][wave][ch in slice]
    const int slice = blockIdx.x & 7;            // XCD-pinned channel slice
    const int cidx  = (AGG_CHUNKS - 1) - (int)(blockIdx.x >> 3);  // LPT order
    const int wave = threadIdx.x >> 6, lane = threadIdx.x & 63;
    const int g = lane >> 3, sub = lane & 7;     // group, 16B channel chunk
    const uint4* s4 = (const uint4*)s;
    const size_t sbase = (size_t)slice * 8 + sub;
    uint4* houtp = hout ? (uint4*)hout + slice * 8 + sub : nullptr;
    const float4 b0 = ((const float4*)bias)[slice * 16 + sub * 2];
    const float4 b1 = ((const float4*)bias)[slice * 16 + sub * 2 + 1];
    const int idx = cidx * AGG_RPB + wave * 8 + g;   // one row per group

    const int beg = rowstart[idx];
    const int end = rowstart[idx + 1];
    float acc[8] = {};
    int j = beg;
    int2 m0, m1, m2, m3, m4, m5, m6, m7;
    if (j < end) {                               // prime the meta pipeline
        const int cl = end - 1;
        m0 = csr_cv[j];
        m1 = csr_cv[(j + 1 < end) ? j + 1 : cl];
        m2 = csr_cv[(j + 2 < end) ? j + 2 : cl];
        m3 = csr_cv[(j + 3 < end) ? j + 3 : cl];
        m4 = csr_cv[(j + 4 < end) ? j + 4 : cl];
        m5 = csr_cv[(j + 5 < end) ? j + 5 : cl];
        m6 = csr_cv[(j + 6 < end) ? j + 6 : cl];
        m7 = csr_cv[(j + 7 < end) ? j + 7 : cl];
    }
    while (j < end) {
        const int jn = j + 8;
        const int cl = end - 1;
        // prefetch next trip's metadata (clamped; overlaps the gathers)
        int2 n0 = csr_cv[(jn     < end) ? jn     : cl];
        int2 n1 = csr_cv[(jn + 1 < end) ? jn + 1 : cl];
        int2 n2 = csr_cv[(jn + 2 < end) ? jn + 2 : cl];
        int2 n3 = csr_cv[(jn + 3 < end) ? jn + 3 : cl];
        int2 n4 = csr_cv[(jn + 4 < end) ? jn + 4 : cl];
        int2 n5 = csr_cv[(jn + 5 < end) ? jn + 5 : cl];
        int2 n6 = csr_cv[(jn + 6 < end) ? jn + 6 : cl];
        int2 n7 = csr_cv[(jn + 7 < end) ? jn + 7 : cl];
        // 8 independent 128B gathers in flight per group
        uint4 v0 = s4[(size_t)m0.x * 64 + sbase];
        uint4 v1 = s4[(size_t)m1.x * 64 + sbase];
        uint4 v2 = s4[(size_t)m2.x * 64 + sbase];
        uint4 v3 = s4[(size_t)m3.x * 64 + sbase];
        uint4 v4 = s4[(size_t)m4.x * 64 + sbase];
        uint4 v5 = s4[(size_t)m5.x * 64 + sbase];
        uint4 v6 = s4[(size_t)m6.x * 64 + sbase];
        uint4 v7 = s4[(size_t)m7.x * 64 + sbase];
        float w0 = __int_as_float(m0.y);         // j < end always valid
        float w1 = (j + 1 < end) ? __int_as_float(m1.y) : 0.f;
        float w2 = (j + 2 < end) ? __int_as_float(m2.y) : 0.f;
        float w3 = (j + 3 < end) ? __int_as_float(m3.y) : 0.f;
        float w4 = (j + 4 < end) ? __int_as_float(m4.y) : 0.f;
        float w5 = (j + 5 < end) ? __int_as_float(m5.y) : 0.f;
        float w6 = (j + 6 < end) ? __int_as_float(m6.y) : 0.f;
        float w7 = (j + 7 < end) ? __int_as_float(m7.y) : 0.f;
        fma8(acc, v0, w0);
        fma8(acc, v1, w1);
        fma8(acc, v2, w2);
        fma8(acc, v3, w3);
        fma8(acc, v4, w4);
        fma8(acc, v5, w5);
        fma8(acc, v6, w6);
        fma8(acc, v7, w7);
        m0 = n0; m1 = n1; m2 = n2; m3 = n3;
        m4 = n4; m5 = n5; m6 = n6; m7 = n7;
        j = jn;
    }
    float pm[8];
    pm[0] = fmaxf(acc[0] + b0.x, 0.f); pm[1] = fmaxf(acc[1] + b0.y, 0.f);
    pm[2] = fmaxf(acc[2] + b0.z, 0.f); pm[3] = fmaxf(acc[3] + b0.w, 0.f);
    pm[4] = fmaxf(acc[4] + b1.x, 0.f); pm[5] = fmaxf(acc[5] + b1.y, 0.f);
    pm[6] = fmaxf(acc[6] + b1.z, 0.f); pm[7] = fmaxf(acc[7] + b1.w, 0.f);
    if (houtp) {
        uint4 ov;
        ov.x = pack2(pm[0], pm[1]); ov.y = pack2(pm[2], pm[3]);
        ov.z = pack2(pm[4], pm[5]); ov.w = pack2(pm[6], pm[7]);
        houtp[(size_t)idx * 64] = ov;
    }
    float ps[8];
    #pragma unroll
    for (int i = 0; i < 8; ++i) ps[i] = pm[i];   // single row: sum == value
    // pooled reduce: over 8 groups in wave, then over waves, then atomics
    #pragma unroll
    for (int off = 8; off <= 32; off <<= 1)
        #pragma unroll
        for (int i = 0; i < 8; ++i) {
            pm[i] = fmaxf(pm[i], __shfl_xor(pm[i], off, 64));
            ps[i] += __shfl_xor(ps[i], off, 64);
        }
    if (g == 0) {
        #pragma unroll
        for (int i = 0; i < 8; ++i) {
            red[0][wave][sub * 8 + i] = pm[i];
            red[1][wave][sub * 8 + i] = ps[i];
        }
    }
    __syncthreads();
    if (threadIdx.x < 64) {
        int ch = threadIdx.x;
        float mx = fmaxf(fmaxf(red[0][0][ch], red[0][1][ch]),
                         fmaxf(red[0][2][ch], red[0][3][ch]));
        float sv = (red[1][0][ch] + red[1][1][ch]) +
                   (red[1][2][ch] + red[1][3][ch]);
        atomicMax((int*)&pmax[slice * 64 + ch], __float_as_int(mx));
        atomicAdd(&psum[slice * 64 + ch], sv);
    }
}

// ---------- pure gemm (layers 2,3) ----------
__global__ __launch_bounds__(256) void gemm_k(const ushort* __restrict__ h,
                                              const ushort* __restrict__ wt,
                                              ushort* __restrict__ s) {
    __shared__ __align__(16) char smem[16384];
    gemm_tile(h, wt, s, nullptr, blockIdx.x, smem);
}

// ---------- head MLP + log_softmax (1024 threads, split-k; proven) ----------
__global__ __launch_bounds__(1024) void mlp_k(const float* __restrict__ pool_max,
                                              const float* __restrict__ pool_sum,
                                              const float* __restrict__ l1W,
                                              const float* __restrict__ l1b,
                                              const float* __restrict__ l2W,
                                              const float* __restrict__ l2b,
                                              const float* __restrict__ l3W,
                                              const float* __restrict__ l3b,
                                              float* __restrict__ out) {
    __shared__ float g[1024];
    __shared__ float part[1024];
    __shared__ float a1[128];
    __shared__ float a2[64];
    __shared__ float a3[10];
    const int tid = threadIdx.x;
    if (tid < 512) {
        g[tid]       = pool_max[tid] + pool_max[512 + tid] + pool_max[1024 + tid];
        g[512 + tid] = (pool_sum[tid] + pool_sum[512 + tid] + pool_sum[1024 + tid]) *
                       (1.0f / N_NODES);
    }
    __syncthreads();
    {
        int ch = tid & 127, sl = tid >> 7;
        float acc = (sl == 0) ? l1b[ch] : 0.f;
        int k0 = sl * 128;
        #pragma unroll 4
        for (int k = k0; k < k0 + 128; ++k) acc += g[k] * l1W[k * 128 + ch];
        part[tid] = acc;
    }
    __syncthreads();
    if (tid < 128) {
        float a = part[tid];
        #pragma unroll
        for (int ss = 1; ss < 8; ++ss) a += part[tid + ss * 128];
        a1[tid] = fmaxf(a, 0.f);
    }
    __syncthreads();
    if (tid < 512) {
        int ch = tid & 63, sl = tid >> 6;
        float acc = (sl == 0) ? l2b[ch] : 0.f;
        int k0 = sl * 16;
        #pragma unroll
        for (int k = k0; k < k0 + 16; ++k) acc += a1[k] * l2W[k * 64 + ch];
        part[tid] = acc;
    }
    __syncthreads();
    if (tid < 64) {
        float a = part[tid];
        #pragma unroll
        for (int ss = 1; ss < 8; ++ss) a += part[tid + ss * 64];
        a2[tid] = fmaxf(a, 0.f);
    }
    __syncthreads();
    if (tid < 10) {
        float acc = l3b[tid];
        for (int k = 0; k < 64; ++k) acc += a2[k] * l3W[k * 10 + tid];
        a3[tid] = acc;
    }
    __syncthreads();
    if (tid == 0) {
        float m = a3[0];
        for (int j = 1; j < 10; ++j) m = fmaxf(m, a3[j]);
        float ssum = 0.f;
        for (int j = 0; j < 10; ++j) ssum += expf(a3[j] - m);
        float lse = m + logf(ssum);
        for (int j = 0; j < 10; ++j) out[j] = a3[j] - lse;
    }
}

extern "C" void kernel_launch(void* const* d_in, const int* in_sizes, int n_in,
                              void* d_out, int out_size, void* d_ws, size_t ws_size,
                              hipStream_t stream) {
    const float* x    = (const float*)d_in[0];
    const int*   rows = (const int*)  d_in[1];
    const int*   cols = (const int*)  d_in[2];
    const float* vals = (const float*)d_in[3];
    const float* W1   = (const float*)d_in[4];
    const float* b1   = (const float*)d_in[5];
    const float* W2   = (const float*)d_in[6];
    const float* b2   = (const float*)d_in[7];
    const float* W3   = (const float*)d_in[8];
    const float* b3   = (const float*)d_in[9];
    const float* l1W  = (const float*)d_in[10];
    const float* l1b  = (const float*)d_in[11];
    const float* l2W  = (const float*)d_in[12];
    const float* l2b  = (const float*)d_in[13];
    const float* l3W  = (const float*)d_in[14];
    const float* l3b  = (const float*)d_in[15];
    float* out = (float*)d_out;

    char* ws = (char*)d_ws;
    size_t off = 0;
    auto alloc = [&](size_t bytes) {
        void* p = ws + off;
        off += (bytes + 255) & ~(size_t)255;
        return p;
    };
    ushort* xb       = (ushort*)alloc((size_t)N_NODES * HD * 2);
    ushort* s        = (ushort*)alloc((size_t)N_NODES * HD * 2);
    ushort* hb       = (ushort*)alloc((size_t)N_NODES * HD * 2);
    ushort* wt1      = (ushort*)alloc((size_t)HD * HD * 2);
    ushort* wt2      = (ushort*)alloc((size_t)HD * HD * 2);
    ushort* wt3      = (ushort*)alloc((size_t)HD * HD * 2);
    // deg/pmax/psum contiguous -> one hipMemsetAsync zeroes all three
    int*    deg      = (int*)   alloc((size_t)N_NODES * 4);
    float*  pmax     = (float*) alloc((size_t)3 * 512 * 4);
    float*  psum     = (float*) alloc((size_t)3 * 512 * 4);
    int*    rowstart = (int*)   alloc((size_t)(N_NODES + 1) * 4);
    int*    cursor   = (int*)   alloc((size_t)N_NODES * 4);
    int2*   csr_cv   = (int2*)  alloc((size_t)N_EDGES * 8);
    int*    inv      = (int*)   alloc((size_t)N_NODES * 4);
    (void)ws_size; (void)in_sizes; (void)n_in; (void)out_size;

    // 0: zero deg+pmax+psum (contiguous)
    hipMemsetAsync(deg, 0, ((size_t)N_NODES * 4 + 255 & ~(size_t)255)
                           + 2 * (((size_t)3 * 512 * 4 + 255) & ~(size_t)255),
                   stream);
    // 1: prep (cvt + wt transpose + edge histogram)
    prep_k<<<NB_CVT + NB_WT + NB_HIST, 256, 0, stream>>>(
        x, xb, W1, W2, W3, wt1, wt2, wt3, rows, deg);
    // 2: degree-sort relabeling (inv) + sorted-space CSR offsets
    scan_k<<<1, 1024, 0, stream>>>(deg, rowstart, cursor, inv);
    // 3: gemm1 (scatter to sorted order) || fill CSR (translated)
    gf1_k<<<628 + 1250, 256, 0, stream>>>(xb, wt1, s, rows, cols, vals, inv,
                                          cursor, csr_cv);
    // 4: agg1 + pool1
    agg_k<<<AGG_BLOCKS, 256, 0, stream>>>(s, rowstart, csr_cv, b1, hb,
                                          pmax, psum);
    // 5: gemm2
    gemm_k<<<628, 256, 0, stream>>>(hb, wt2, s);
    // 6: agg2 + pool2
    agg_k<<<AGG_BLOCKS, 256, 0, stream>>>(s, rowstart, csr_cv, b2, hb,
                                          pmax + 512, psum + 512);
    // 7: gemm3
    gemm_k<<<628, 256, 0, stream>>>(hb, wt3, s);
    // 8: agg3 + pool3 (no hb write -- output only needed for pooling)
    agg_k<<<AGG_BLOCKS, 256, 0, stream>>>(s, rowstart, csr_cv, b3, nullptr,
                                          pmax + 1024, psum + 1024);
    // 9: mlp head
    mlp_k<<<1, 1024, 0, stream>>>(pmax, psum, l1W, l1b, l2W, l2b, l3W, l3b, out);
}

// Round 12
// 332.113 us; speedup vs baseline: 1.0381x; 1.0381x over previous
//
#include <hip/hip_runtime.h>
#include <hip/hip_bf16.h>

#define N_NODES 20000
#define N_EDGES 320000
#define HD 512

typedef __attribute__((ext_vector_type(8))) short bf16x8;
typedef __attribute__((ext_vector_type(4))) float f32x4;

// ---------- bf16 helpers ----------
__device__ inline ushort f2bf(float f) {
    uint u = __float_as_uint(f);
    uint r = (u + 0x7fffu + ((u >> 16) & 1u)) >> 16;
    return (ushort)r;
}
__device__ inline uint pack2(float a, float b) {
    return (uint)f2bf(a) | ((uint)f2bf(b) << 16);
}
__device__ inline float bflo(uint u) { return __uint_as_float(u << 16); }
__device__ inline float bfhi(uint u) { return __uint_as_float(u & 0xffff0000u); }

__device__ __forceinline__ void async_load16(const void* g, void* l) {
    __builtin_amdgcn_global_load_lds(
        (const __attribute__((address_space(1))) uint*)g,
        (__attribute__((address_space(3))) uint*)l,
        16, 0, 0);
}

// ---------- gemm tile: 128x128, BK=32 (r9 measured optimum) -----------------
// remap != nullptr: C-row gr stored at row remap[gr] (gemm1 sorted scatter).
__device__ __forceinline__ void gemm_tile(const ushort* __restrict__ A,
                                          const ushort* __restrict__ Bt,
                                          ushort* __restrict__ C,
                                          const int* __restrict__ remap,
                                          int tile, char* smem) {
    short* As = (short*)smem;
    short* Bs = (short*)(smem + 128 * 32 * 2);
    const int tid = threadIdx.x;
    const int lane = tid & 63;
    const int wave = tid >> 6;
    const int l15 = lane & 15;
    const int q = lane >> 4;
    const int wrow = wave >> 1, wcol = wave & 1;
    const int row0 = (tile >> 2) * 128;
    const int col0 = (tile & 3) * 128;

    const int srow = lane >> 2;
    const int kc   = (lane & 3) ^ ((lane >> 3) & 3);
    const int sl   = (l15 >> 1) & 3;

    f32x4 acc[4][4] = {};

    for (int k0 = 0; k0 < HD; k0 += 32) {
        #pragma unroll
        for (int l = 0; l < 2; ++l) {
            const int rbase = wave * 32 + l * 16;
            const ushort* ga = &A [(size_t)(row0 + rbase + srow) * HD + k0 + kc * 8];
            const ushort* gb = &Bt[(size_t)(col0 + rbase + srow) * HD + k0 + kc * 8];
            async_load16(ga, &As[rbase * 32]);
            async_load16(gb, &Bs[rbase * 32]);
        }
        __syncthreads();
        bf16x8 aF[4], bF[4];
        #pragma unroll
        for (int i = 0; i < 4; ++i)
            aF[i] = *(bf16x8*)&As[(wrow * 64 + i * 16 + l15) * 32 + (q ^ sl) * 8];
        #pragma unroll
        for (int j = 0; j < 4; ++j)
            bF[j] = *(bf16x8*)&Bs[(wcol * 64 + j * 16 + l15) * 32 + (q ^ sl) * 8];
        #pragma unroll
        for (int i = 0; i < 4; ++i)
            #pragma unroll
            for (int j = 0; j < 4; ++j)
                acc[i][j] = __builtin_amdgcn_mfma_f32_16x16x32_bf16(aF[i], bF[j], acc[i][j], 0, 0, 0);
        __syncthreads();
    }
    #pragma unroll
    for (int i = 0; i < 4; ++i) {
        #pragma unroll
        for (int r = 0; r < 4; ++r) {
            int gr = row0 + wrow * 64 + i * 16 + q * 4 + r;
            if (gr < N_NODES) {
                int orow = remap ? remap[gr] : gr;
                #pragma unroll
                for (int j = 0; j < 4; ++j) {
                    int gc = col0 + wcol * 64 + j * 16 + l15;
                    C[(size_t)orow * HD + gc] = f2bf(acc[i][j][r]);
                }
            }
        }
    }
}

// ---------- prep: cvt x | wt transpose | edge histogram -----------------
#define NB_CVT 5000
#define NB_WT  192
#define NB_HIST 1250
__global__ __launch_bounds__(256) void prep_k(const float* __restrict__ x,
                                              ushort* __restrict__ xb,
                                              const float* __restrict__ W1,
                                              const float* __restrict__ W2,
                                              const float* __restrict__ W3,
                                              ushort* __restrict__ T1,
                                              ushort* __restrict__ T2,
                                              ushort* __restrict__ T3,
                                              const int* __restrict__ rows,
                                              int* __restrict__ deg) {
    __shared__ float t[64][65];
    const int b = blockIdx.x;
    const int tid = threadIdx.x;
    if (b < NB_CVT) {
        int c = b * 256 + tid;
        const float4* p = (const float4*)x + (size_t)c * 2;
        float4 a = p[0], q = p[1];
        uint4 o;
        o.x = pack2(a.x, a.y); o.y = pack2(a.z, a.w);
        o.z = pack2(q.x, q.y); o.w = pack2(q.z, q.w);
        ((uint4*)xb)[c] = o;
    } else if (b < NB_CVT + NB_WT) {
        int idx = b - NB_CVT;
        int layer = idx >> 6, rem = idx & 63;
        const float* W = (layer == 0) ? W1 : (layer == 1) ? W2 : W3;
        ushort* T      = (layer == 0) ? T1 : (layer == 1) ? T2 : T3;
        int kb = (rem >> 3) * 64, nb = (rem & 7) * 64;
        int c = tid & 63, r4 = tid >> 6;
        #pragma unroll
        for (int l = 0; l < 16; ++l) {
            int r = l * 4 + r4;
            t[r][c] = W[(size_t)(kb + r) * HD + nb + c];
        }
        __syncthreads();
        #pragma unroll
        for (int l = 0; l < 16; ++l) {
            int r = l * 4 + r4;
            T[(size_t)(nb + r) * HD + kb + c] = f2bf(t[c][r]);
        }
    } else {
        int e = (b - NB_CVT - NB_WT) * 256 + tid;  // 1250*256 == N_EDGES
        atomicAdd(&deg[rows[e]], 1);
    }
}

// ---------- scan: degree-sort relabeling, one workgroup (proven r8) ---------
__global__ __launch_bounds__(1024) void scan_k(const int* __restrict__ deg,
                                               int* __restrict__ rowstart,
                                               int* __restrict__ cursor,
                                               int* __restrict__ inv) {
    __shared__ int hist[256];
    __shared__ int boff0[256];
    __shared__ int bcur[256];
    __shared__ int ebase[256];
    const int tid = threadIdx.x;
    if (tid < 256) hist[tid] = 0;
    __syncthreads();
    for (int base = 0; base < N_NODES; base += 1024) {   // pass 1: histogram
        int i = base + tid;
        if (i < N_NODES) {
            int d = deg[i]; if (d > 255) d = 255;
            atomicAdd(&hist[d], 1);
        }
    }
    __syncthreads();
    if (tid == 0) {
        int a = 0, e = 0;
        for (int d = 0; d < 256; ++d) {
            boff0[d] = a; bcur[d] = a; ebase[d] = e;
            a += hist[d]; e += hist[d] * d;
        }
    }
    __syncthreads();
    for (int base = 0; base < N_NODES; base += 1024) {   // pass 2: inv scatter
        int i = base + tid;
        if (i < N_NODES) {
            int d = deg[i]; if (d > 255) d = 255;
            int p = atomicAdd(&bcur[d], 1);
            inv[i] = p;
        }
    }
    __syncthreads();
    for (int base = 0; base < N_NODES; base += 1024) {   // pass 3: rowstart
        int p = base + tid;
        if (p < N_NODES) {
            int d = 0;                                    // max d: boff0[d]<=p
            #pragma unroll
            for (int step = 128; step; step >>= 1)
                if (d + step < 256 && boff0[d + step] <= p) d += step;
            int rs = ebase[d] + (p - boff0[d]) * d;
            rowstart[p] = rs;
            cursor[p]   = rs;
        }
    }
    if (tid == 0) rowstart[N_NODES] = N_EDGES;
}

// ---------- gemm1 (inv-scatter epilogue) || fill CSR (translated) -----------
__global__ __launch_bounds__(256) void gf1_k(const ushort* __restrict__ xb,
                                             const ushort* __restrict__ wt1,
                                             ushort* __restrict__ s,
                                             const int* __restrict__ rows,
                                             const int* __restrict__ cols,
                                             const float* __restrict__ vals,
                                             const int* __restrict__ inv,
                                             int* __restrict__ cursor,
                                             int2* __restrict__ csr_cv) {
    __shared__ __align__(16) char smem[16384];
    const int b = blockIdx.x;
    if (b < 628) {
        gemm_tile(xb, wt1, s, inv, b, smem);     // s lands in sorted order
    } else {
        int e = (b - 628) * 256 + threadIdx.x;   // 1250*256 == N_EDGES exactly
        int rp = inv[rows[e]];                   // sorted row id
        int cp = inv[cols[e]];                   // sorted col id (s is sorted)
        int p = atomicAdd(&cursor[rp], 1);
        csr_cv[p] = make_int2(cp, __float_as_int(vals[e]));
    }
}

// ---------- aggregate (r9 measured optimum): sorted space + fused pool ------
// Degree-sorted node space (row == idx): wave's rows consecutive AND
// equal-degree; metadata one contiguous stream; hout contiguous. LPT via
// reversed cidx. XCD-pinned 64-ch slices (L2-resident gather, FETCH 21MB).
// 4-deep branchless gather pipeline (depth-8 measured WORSE, r11; RPG=1
// measured neutral, r10). Fused max/mean pool epilogue deletes the pool
// dispatches + 60MB traffic (r9: -48us).
__device__ inline void fma8(float* acc, uint4 v, float w) {
    acc[0] += w * bflo(v.x); acc[1] += w * bfhi(v.x);
    acc[2] += w * bflo(v.y); acc[3] += w * bfhi(v.y);
    acc[4] += w * bflo(v.z); acc[5] += w * bfhi(v.z);
    acc[6] += w * bflo(v.w); acc[7] += w * bfhi(v.w);
}

#define RPG 2                                    // rows per 8-lane group
#define AGG_RPB (32 * RPG)                       // 64 rows per block
#define AGG_CHUNKS ((N_NODES + AGG_RPB - 1) / AGG_RPB)   // 313
#define AGG_BLOCKS (8 * AGG_CHUNKS)              // 2504

__global__ __launch_bounds__(256) void agg_k(const ushort* __restrict__ s,
                                             const int* __restrict__ rowstart,
                                             const int2* __restrict__ csr_cv,
                                             const float* __restrict__ bias,
                                             ushort* __restrict__ hout,
                                             float* __restrict__ pmax,
                                             float* __restrict__ psum) {
    __shared__ float red[2][4][64];              // [max|sum][wave][ch in slice]
    const int slice = blockIdx.x & 7;            // XCD-pinned channel slice
    const int cidx  = (AGG_CHUNKS - 1) - (int)(blockIdx.x >> 3);  // LPT order
    const int wave = threadIdx.x >> 6, lane = threadIdx.x & 63;
    const int g = lane >> 3, sub = lane & 7;     // group, 16B channel chunk
    const uint4* s4 = (const uint4*)s;
    const size_t sbase = (size_t)slice * 8 + sub;
    uint4* houtp = hout ? (uint4*)hout + slice * 8 + sub : nullptr;
    const float4 b0 = ((const float4*)bias)[slice * 16 + sub * 2];
    const float4 b1 = ((const float4*)bias)[slice * 16 + sub * 2 + 1];
    const int ibase = cidx * AGG_RPB + wave * (8 * RPG) + g * RPG;
    float pm[8] = {}, ps[8] = {};                // pooled max/sum (relu >= 0)

    #pragma unroll
    for (int rr = 0; rr < RPG; ++rr) {
        const int idx = ibase + rr;              // == row (sorted space)
        int beg = 0, end = 0;
        if (idx < N_NODES) {
            beg = rowstart[idx];
            end = rowstart[idx + 1];
        }
        float acc[8] = {};
        int j = beg;
        int2 m0, m1, m2, m3;
        if (j < end) {                           // prime the meta pipeline
            m0 = csr_cv[j];
            m1 = csr_cv[(j + 1 < end) ? j + 1 : end - 1];
            m2 = csr_cv[(j + 2 < end) ? j + 2 : end - 1];
            m3 = csr_cv[(j + 3 < end) ? j + 3 : end - 1];
        }
        while (j < end) {
            const int jn = j + 4;
            const int cl = end - 1;
            int2 n0 = csr_cv[(jn     < end) ? jn     : cl];
            int2 n1 = csr_cv[(jn + 1 < end) ? jn + 1 : cl];
            int2 n2 = csr_cv[(jn + 2 < end) ? jn + 2 : cl];
            int2 n3 = csr_cv[(jn + 3 < end) ? jn + 3 : cl];
            uint4 v0 = s4[(size_t)m0.x * 64 + sbase];
            uint4 v1 = s4[(size_t)m1.x * 64 + sbase];
            uint4 v2 = s4[(size_t)m2.x * 64 + sbase];
            uint4 v3 = s4[(size_t)m3.x * 64 + sbase];
            float w0 = __int_as_float(m0.y);
            float w1 = (j + 1 < end) ? __int_as_float(m1.y) : 0.f;
            float w2 = (j + 2 < end) ? __int_as_float(m2.y) : 0.f;
            float w3 = (j + 3 < end) ? __int_as_float(m3.y) : 0.f;
            fma8(acc, v0, w0);
            fma8(acc, v1, w1);
            fma8(acc, v2, w2);
            fma8(acc, v3, w3);
            m0 = n0; m1 = n1; m2 = n2; m3 = n3;
            j = jn;
        }
        if (idx < N_NODES) {
            float o[8];
            o[0] = fmaxf(acc[0] + b0.x, 0.f); o[1] = fmaxf(acc[1] + b0.y, 0.f);
            o[2] = fmaxf(acc[2] + b0.z, 0.f); o[3] = fmaxf(acc[3] + b0.w, 0.f);
            o[4] = fmaxf(acc[4] + b1.x, 0.f); o[5] = fmaxf(acc[5] + b1.y, 0.f);
            o[6] = fmaxf(acc[6] + b1.z, 0.f); o[7] = fmaxf(acc[7] + b1.w, 0.f);
            #pragma unroll
            for (int i = 0; i < 8; ++i) {
                pm[i] = fmaxf(pm[i], o[i]);
                ps[i] += o[i];
            }
            if (houtp) {
                uint4 ov;
                ov.x = pack2(o[0], o[1]); ov.y = pack2(o[2], o[3]);
                ov.z = pack2(o[4], o[5]); ov.w = pack2(o[6], o[7]);
                houtp[(size_t)idx * 64] = ov;
            }
        }
    }
    // pooled reduce: over 8 groups in wave (lane bits 3..5), then over waves
    #pragma unroll
    for (int off = 8; off <= 32; off <<= 1)
        #pragma unroll
        for (int i = 0; i < 8; ++i) {
            pm[i] = fmaxf(pm[i], __shfl_xor(pm[i], off, 64));
            ps[i] += __shfl_xor(ps[i], off, 64);
        }
    if (g == 0) {
        #pragma unroll
        for (int i = 0; i < 8; ++i) {
            red[0][wave][sub * 8 + i] = pm[i];
            red[1][wave][sub * 8 + i] = ps[i];
        }
    }
    __syncthreads();
    if (threadIdx.x < 64) {
        int ch = threadIdx.x;
        float mx = fmaxf(fmaxf(red[0][0][ch], red[0][1][ch]),
                         fmaxf(red[0][2][ch], red[0][3][ch]));
        float sv = (red[1][0][ch] + red[1][1][ch]) +
                   (red[1][2][ch] + red[1][3][ch]);
        atomicMax((int*)&pmax[slice * 64 + ch], __float_as_int(mx));
        atomicAdd(&psum[slice * 64 + ch], sv);
    }
}

// ---------- pure gemm (layers 2,3) ----------
__global__ __launch_bounds__(256) void gemm_k(const ushort* __restrict__ h,
                                              const ushort* __restrict__ wt,
                                              ushort* __restrict__ s) {
    __shared__ __align__(16) char smem[16384];
    gemm_tile(h, wt, s, nullptr, blockIdx.x, smem);
}

// ---------- head MLP + log_softmax (1024 threads, split-k; proven) ----------
__global__ __launch_bounds__(1024) void mlp_k(const float* __restrict__ pool_max,
                                              const float* __restrict__ pool_sum,
                                              const float* __restrict__ l1W,
                                              const float* __restrict__ l1b,
                                              const float* __restrict__ l2W,
                                              const float* __restrict__ l2b,
                                              const float* __restrict__ l3W,
                                              const float* __restrict__ l3b,
                                              float* __restrict__ out) {
    __shared__ float g[1024];
    __shared__ float part[1024];
    __shared__ float a1[128];
    __shared__ float a2[64];
    __shared__ float a3[10];
    const int tid = threadIdx.x;
    if (tid < 512) {
        g[tid]       = pool_max[tid] + pool_max[512 + tid] + pool_max[1024 + tid];
        g[512 + tid] = (pool_sum[tid] + pool_sum[512 + tid] + pool_sum[1024 + tid]) *
                       (1.0f / N_NODES);
    }
    __syncthreads();
    {
        int ch = tid & 127, sl = tid >> 7;
        float acc = (sl == 0) ? l1b[ch] : 0.f;
        int k0 = sl * 128;
        #pragma unroll 4
        for (int k = k0; k < k0 + 128; ++k) acc += g[k] * l1W[k * 128 + ch];
        part[tid] = acc;
    }
    __syncthreads();
    if (tid < 128) {
        float a = part[tid];
        #pragma unroll
        for (int ss = 1; ss < 8; ++ss) a += part[tid + ss * 128];
        a1[tid] = fmaxf(a, 0.f);
    }
    __syncthreads();
    if (tid < 512) {
        int ch = tid & 63, sl = tid >> 6;
        float acc = (sl == 0) ? l2b[ch] : 0.f;
        int k0 = sl * 16;
        #pragma unroll
        for (int k = k0; k < k0 + 16; ++k) acc += a1[k] * l2W[k * 64 + ch];
        part[tid] = acc;
    }
    __syncthreads();
    if (tid < 64) {
        float a = part[tid];
        #pragma unroll
        for (int ss = 1; ss < 8; ++ss) a += part[tid + ss * 64];
        a2[tid] = fmaxf(a, 0.f);
    }
    __syncthreads();
    if (tid < 10) {
        float acc = l3b[tid];
        for (int k = 0; k < 64; ++k) acc += a2[k] * l3W[k * 10 + tid];
        a3[tid] = acc;
    }
    __syncthreads();
    if (tid == 0) {
        float m = a3[0];
        for (int j = 1; j < 10; ++j) m = fmaxf(m, a3[j]);
        float ssum = 0.f;
        for (int j = 0; j < 10; ++j) ssum += expf(a3[j] - m);
        float lse = m + logf(ssum);
        for (int j = 0; j < 10; ++j) out[j] = a3[j] - lse;
    }
}

extern "C" void kernel_launch(void* const* d_in, const int* in_sizes, int n_in,
                              void* d_out, int out_size, void* d_ws, size_t ws_size,
                              hipStream_t stream) {
    const float* x    = (const float*)d_in[0];
    const int*   rows = (const int*)  d_in[1];
    const int*   cols = (const int*)  d_in[2];
    const float* vals = (const float*)d_in[3];
    const float* W1   = (const float*)d_in[4];
    const float* b1   = (const float*)d_in[5];
    const float* W2   = (const float*)d_in[6];
    const float* b2   = (const float*)d_in[7];
    const float* W3   = (const float*)d_in[8];
    const float* b3   = (const float*)d_in[9];
    const float* l1W  = (const float*)d_in[10];
    const float* l1b  = (const float*)d_in[11];
    const float* l2W  = (const float*)d_in[12];
    const float* l2b  = (const float*)d_in[13];
    const float* l3W  = (const float*)d_in[14];
    const float* l3b  = (const float*)d_in[15];
    float* out = (float*)d_out;

    char* ws = (char*)d_ws;
    size_t off = 0;
    auto alloc = [&](size_t bytes) {
        void* p = ws + off;
        off += (bytes + 255) & ~(size_t)255;
        return p;
    };
    ushort* xb       = (ushort*)alloc((size_t)N_NODES * HD * 2);
    ushort* s        = (ushort*)alloc((size_t)N_NODES * HD * 2);
    ushort* hb       = (ushort*)alloc((size_t)N_NODES * HD * 2);
    ushort* wt1      = (ushort*)alloc((size_t)HD * HD * 2);
    ushort* wt2      = (ushort*)alloc((size_t)HD * HD * 2);
    ushort* wt3      = (ushort*)alloc((size_t)HD * HD * 2);
    // deg/pmax/psum contiguous -> one hipMemsetAsync zeroes all three
    int*    deg      = (int*)   alloc((size_t)N_NODES * 4);
    float*  pmax     = (float*) alloc((size_t)3 * 512 * 4);
    float*  psum     = (float*) alloc((size_t)3 * 512 * 4);
    int*    rowstart = (int*)   alloc((size_t)(N_NODES + 1) * 4);
    int*    cursor   = (int*)   alloc((size_t)N_NODES * 4);
    int2*   csr_cv   = (int2*)  alloc((size_t)N_EDGES * 8);
    int*    inv      = (int*)   alloc((size_t)N_NODES * 4);
    (void)ws_size; (void)in_sizes; (void)n_in; (void)out_size;

    // 0: zero deg+pmax+psum (contiguous)
    hipMemsetAsync(deg, 0, ((size_t)N_NODES * 4 + 255 & ~(size_t)255)
                           + 2 * (((size_t)3 * 512 * 4 + 255) & ~(size_t)255),
                   stream);
    // 1: prep (cvt + wt transpose + edge histogram)
    prep_k<<<NB_CVT + NB_WT + NB_HIST, 256, 0, stream>>>(
        x, xb, W1, W2, W3, wt1, wt2, wt3, rows, deg);
    // 2: degree-sort relabeling (inv) + sorted-space CSR offsets
    scan_k<<<1, 1024, 0, stream>>>(deg, rowstart, cursor, inv);
    // 3: gemm1 (scatter to sorted order) || fill CSR (translated)
    gf1_k<<<628 + 1250, 256, 0, stream>>>(xb, wt1, s, rows, cols, vals, inv,
                                          cursor, csr_cv);
    // 4: agg1 + pool1
    agg_k<<<AGG_BLOCKS, 256, 0, stream>>>(s, rowstart, csr_cv, b1, hb,
                                          pmax, psum);
    // 5: gemm2
    gemm_k<<<628, 256, 0, stream>>>(hb, wt2, s);
    // 6: agg2 + pool2
    agg_k<<<AGG_BLOCKS, 256, 0, stream>>>(s, rowstart, csr_cv, b2, hb,
                                          pmax + 512, psum + 512);
    // 7: gemm3
    gemm_k<<<628, 256, 0, stream>>>(hb, wt3, s);
    // 8: agg3 + pool3 (no hb write -- output only needed for pooling)
    agg_k<<<AGG_BLOCKS, 256, 0, stream>>>(s, rowstart, csr_cv, b3, nullptr,
                                          pmax + 1024, psum + 1024);
    // 9: mlp head
    mlp_k<<<1, 1024, 0, stream>>>(pmax, psum, l1W, l1b, l2W, l2b, l3W, l3b, out);
}